// Round 17
// baseline (146.180 us; speedup 1.0000x reference)
//
#include <hip/hip_runtime.h>
#include <cstdint>
#include <cstddef>

#define B 128
#define P 8732
#define NC 21
#define O 16
#define THRESH 0.5f
#define NB1 8        // pass1 blocks per image
#define NBX2 4       // scores blocks per image
#define BPB 2304     // priors per scores block
#define WPW 576      // priors per wave (9 chunks of 64)
#define SLABF 1536   // padded slab floats: 6 DMA instrs x 64 lanes x 4 floats
#define SCORE_BLKS (B * NBX2)   // 512
#define P1_BLKS (B * NB1)       // 1024

typedef unsigned long long u64;
typedef unsigned int u32;
typedef unsigned char u8;

#define VMW(n) asm volatile("s_waitcnt vmcnt(" #n ")" ::: "memory")

__device__ __forceinline__ float iou_pt(float a0, float a1, float a2, float a3,
                                        float b0, float b1, float b2, float b3) {
    float ltx = fmaxf(a0, b0), lty = fmaxf(a1, b1);
    float rbx = fminf(a2, b2), rby = fminf(a3, b3);
    float wx = fmaxf(rbx - ltx, 0.0f), wy = fmaxf(rby - lty, 0.0f);
    float inter = wx * wy;
    float aa = (a2 - a0) * (a3 - a1);
    float ab = (b2 - b0) * (b3 - b1);
    return inter / (aa + ab - inter);
}

// Stage one 64-prior score chunk into a wave-private padded LDS slab via
// global_load_lds DMA (6 instrs, all lanes, vmcnt exact; clamped global src;
// LDS overflow lands in never-read pad).
__device__ __forceinline__ void stage64(const float* __restrict__ gsrc,
                                        float* lds, int nf4, int lane) {
    const char* src = (const char*)gsrc;
    char* dst = (char*)lds;
#pragma unroll
    for (int i = 0; i < 6; i++) {
        int idx = i * 64 + lane;
        if (idx >= nf4) idx = nf4 - 1;
        __builtin_amdgcn_global_load_lds(
            (const __attribute__((address_space(1))) u32*)(src + (size_t)idx * 16),
            (__attribute__((address_space(3))) u32*)(dst + i * 1024),
            16, 0, 0);
    }
}

// k_main: block-partitioned fusion of (a) the pure scores stream (mine0 =
// lse - fs[0] for every prior; NO other VMEM in the chunk loop, so the
// counted vmcnt pipeline is never drained by compiler-inserted waits) and
// (b) pass1 IoU matching (independent work, hides in (a)'s latency bubbles).
__global__ void __launch_bounds__(256) k_main(const float* __restrict__ gt,
                                              const float* __restrict__ priors,
                                              const float* __restrict__ scores,
                                              u64* __restrict__ bk,
                                              u8* __restrict__ bidx,
                                              float* __restrict__ mine) {
    __shared__ union {
        float slab[4][3][SLABF];                       // 73728 B (scores path)
        struct { u64 wk[4][O]; float gt4[O * 4]; } p1; // pass1 path
    } sm;
    const int tid = threadIdx.x;
    const int wave = tid >> 6, lane = tid & 63;
    const int bid = blockIdx.x;

    if (bid < SCORE_BLKS) {
        // ---------- scores path: wave-synchronous triple-buffered DMA ----------
        const int b = bid >> 2;
        const int bx = bid & 3;
        const int wbase = bx * BPB + wave * WPW;
        int wp = P - wbase; if (wp > WPW) wp = WPW;
        const int nchunk = (wp + 63) >> 6;   // 9 or 2; wp >= 92 always

        // prologue: stage up to 3 chunks
        for (int c0 = 0; c0 < 3 && c0 < nchunk; ++c0) {
            int nv0 = wp - c0 * 64; if (nv0 > 64) nv0 = 64;
            stage64(scores + ((size_t)b * P + wbase + c0 * 64) * NC,
                    &sm.slab[wave][c0][0], nv0 * 21 / 4, lane);
        }
        for (int c = 0; c < nchunk; ++c) {
            const int base = wbase + c * 64;
            int nv = wp - c * 64; if (nv > 64) nv = 64;
            int ahead = nchunk - 1 - c; if (ahead > 2) ahead = 2;
            // exact counts: 6*ahead DMAs + min(c,2) in-flight mine stores are
            // newer than chunk c's stage group
            if (ahead == 2) {
                if (c == 0) VMW(12); else if (c == 1) VMW(13); else VMW(14);
            } else if (ahead == 1) {
                if (c == 0) VMW(6); else if (c == 1) VMW(7); else VMW(8);
            } else {
                VMW(0);
            }
            __builtin_amdgcn_sched_barrier(0);

            if (lane < nv) {
                const float* fsl = &sm.slab[wave][c % 3][lane * NC];
                float fs[NC];
#pragma unroll
                for (int cc = 0; cc < NC; cc++) fs[cc] = fsl[cc];  // stride-21: 2-way bank = free

                float mx = fs[0];
#pragma unroll
                for (int cc = 1; cc < NC; cc++) mx = fmaxf(mx, fs[cc]);
                float se = 0.0f;
#pragma unroll
                for (int cc = 0; cc < NC; cc++) se += __expf(fs[cc] - mx);
                float lse = mx + __logf(se);
                mine[(size_t)b * P + base + lane] = lse - fs[0];   // the only non-DMA VMEM
            }

            if (c + 3 < nchunk) {
                int nv3 = wp - (c + 3) * 64; if (nv3 > 64) nv3 = 64;
                asm volatile("s_waitcnt lgkmcnt(0)" ::: "memory");  // drain slab reads before overwrite
                stage64(scores + ((size_t)b * P + base + 3 * 64) * NC,
                        &sm.slab[wave][c % 3][0], nv3 * 21 / 4, lane);
            }
        }
    } else {
        // ---------- pass1 path: IoU matching ----------
        const int pid = bid - SCORE_BLKS;
        const int bx = pid & 7;
        const int b = pid >> 3;
        if (tid < O * 4) {
            int o = tid >> 2, c = tid & 3;
            sm.p1.gt4[tid] = gt[(b * O + o) * 5 + c];
        }
        __syncthreads();

        u64 lk[O];
#pragma unroll
        for (int o = 0; o < O; o++) lk[o] = 0ull;

        for (int p = bx * 256 + tid; p < P; p += NB1 * 256) {
            float4 pr = reinterpret_cast<const float4*>(priors)[p];
            float b0 = pr.x - pr.z * 0.5f, b1 = pr.y - pr.w * 0.5f;
            float b2 = pr.x + pr.z * 0.5f, b3 = pr.y + pr.w * 0.5f;
            float bov = -1.0f; int bo = 0;
#pragma unroll
            for (int o = 0; o < O; o++) {
                float v = iou_pt(sm.p1.gt4[o * 4 + 0], sm.p1.gt4[o * 4 + 1],
                                 sm.p1.gt4[o * 4 + 2], sm.p1.gt4[o * 4 + 3],
                                 b0, b1, b2, b3);
                u64 key = ((u64)__float_as_uint(v) << 32) | (u64)(0xFFFFFFFFu - (u32)p);
                lk[o] = (key > lk[o]) ? key : lk[o];
                if (v > bov) { bov = v; bo = o; }   // first occurrence on tie
            }
            bidx[(size_t)b * P + p] = (u8)(bo | ((bov >= THRESH) ? 0x80 : 0));
        }

#pragma unroll
        for (int o = 0; o < O; o++) {
            u64 k = lk[o];
#pragma unroll
            for (int off = 32; off > 0; off >>= 1) {
                u64 other = (u64)__shfl_xor((long long)k, off, 64);
                k = (other > k) ? other : k;
            }
            if (lane == 0) sm.p1.wk[wave][o] = k;
        }
        __syncthreads();
        if (tid < O) {
            u64 k = sm.p1.wk[0][tid];
#pragma unroll
            for (int w = 1; w < 4; w++) { u64 v = sm.p1.wk[w][tid]; k = (v > k) ? v : k; }
            bk[((size_t)b * O + tid) * NB1 + bx] = k;
        }
    }
}

// k_fix: one block per image. Resolves the override from bk, scans bidx for
// positives (~1%), recomputes their ce sparsely, patches mine=0, accumulates
// np/ce/loc per image. Also zeroes acc/ticket for k_hardneg.
__global__ void __launch_bounds__(256) k_fix(const float* __restrict__ gt,
                                             const float* __restrict__ priors,
                                             const float* __restrict__ loc_preds,
                                             const float* __restrict__ scores,
                                             const u64* __restrict__ bk,
                                             const u8* __restrict__ bidx,
                                             float* __restrict__ mine,
                                             int* __restrict__ npA,
                                             double* __restrict__ plA,
                                             double* __restrict__ pcA,
                                             double* __restrict__ acc,
                                             u32* __restrict__ ticket) {
    const int b = blockIdx.x;
    const int tid = threadIdx.x;
    const int lane = tid & 63, wave = tid >> 6;
    __shared__ float s_gt[O * 5];
    __shared__ int s_ovr[O];
    __shared__ double s_l[4], s_c[4];
    __shared__ int s_n[4];

    if (b == 0 && tid == 0) { acc[0] = 0.0; *ticket = 0u; }
    if (tid < O * 5) s_gt[tid] = gt[b * O * 5 + tid];
    if (tid < O) {
        u64 k = bk[((size_t)b * O + tid) * NB1];
#pragma unroll
        for (int i = 1; i < NB1; i++) {
            u64 v = bk[((size_t)b * O + tid) * NB1 + i];
            k = (v > k) ? v : k;
        }
        s_ovr[tid] = (int)(0xFFFFFFFFu - (u32)(k & 0xFFFFFFFFull));
    }
    __syncthreads();

    float l_loc = 0.f, l_ce = 0.f;
    int l_np = 0;

    for (int i4 = tid; i4 < P / 4; i4 += 256) {
        u32 w = *reinterpret_cast<const u32*>(bidx + (size_t)b * P + i4 * 4);
#pragma unroll
        for (int j = 0; j < 4; j++) {
            const int p = i4 * 4 + j;
            int e = (int)((w >> (8 * j)) & 0xFFu);
#pragma unroll
            for (int o = 0; o < O; o++)
                if (s_ovr[o] == p) e = o | 0x80;   // ascending: last wins
            if (e & 0x80) {
                int best_idx = e & 0x3F;
                int cls = (int)s_gt[best_idx * 5 + 4];

                const float* sp = scores + ((size_t)b * P + p) * NC;
                float fs[NC];
#pragma unroll
                for (int cc = 0; cc < NC; cc++) fs[cc] = sp[cc];
                float mx = fs[0];
#pragma unroll
                for (int cc = 1; cc < NC; cc++) mx = fmaxf(mx, fs[cc]);
                float se = 0.0f;
#pragma unroll
                for (int cc = 0; cc < NC; cc++) se += __expf(fs[cc] - mx);
                float lse = mx + __logf(se);
                float g = fs[0];
#pragma unroll
                for (int cc = 1; cc < NC; cc++) g = (cc == cls) ? fs[cc] : g;
                float ce = lse - g;

                mine[(size_t)b * P + p] = 0.0f;
                l_np++;
                l_ce += ce;

                float4 pr = reinterpret_cast<const float4*>(priors)[p];
                float m0 = s_gt[best_idx * 5 + 0], m1 = s_gt[best_idx * 5 + 1];
                float m2 = s_gt[best_idx * 5 + 2], m3 = s_gt[best_idx * 5 + 3];
                float tx = ((m0 + m2) * 0.5f - pr.x) / (0.1f * pr.z);
                float ty = ((m1 + m3) * 0.5f - pr.y) / (0.1f * pr.w);
                float tw = __logf((m2 - m0) / pr.z) * 5.0f;
                float th = __logf((m3 - m1) / pr.w) * 5.0f;
                float4 lp = reinterpret_cast<const float4*>(loc_preds)[(size_t)b * P + p];
                float d0 = fabsf(lp.x - tx), d1 = fabsf(lp.y - ty);
                float d2 = fabsf(lp.z - tw), d3 = fabsf(lp.w - th);
                float s0 = d0 < 1.0f ? 0.5f * d0 * d0 : d0 - 0.5f;
                float s1 = d1 < 1.0f ? 0.5f * d1 * d1 : d1 - 0.5f;
                float s2 = d2 < 1.0f ? 0.5f * d2 * d2 : d2 - 0.5f;
                float s3 = d3 < 1.0f ? 0.5f * d3 * d3 : d3 - 0.5f;
                l_loc += (s0 + s1) + (s2 + s3);
            }
        }
    }

#pragma unroll
    for (int off = 32; off > 0; off >>= 1) {
        l_loc += __shfl_xor(l_loc, off, 64);
        l_ce  += __shfl_xor(l_ce, off, 64);
        l_np  += __shfl_xor(l_np, off, 64);
    }
    if (lane == 0) { s_l[wave] = (double)l_loc; s_c[wave] = (double)l_ce; s_n[wave] = l_np; }
    __syncthreads();
    if (tid == 0) {
        plA[b] = (s_l[0] + s_l[1]) + (s_l[2] + s_l[3]);
        pcA[b] = (s_c[0] + s_c[1]) + (s_c[2] + s_c[3]);
        npA[b] = s_n[0] + s_n[1] + s_n[2] + s_n[3];
    }
}

// k_hardneg: top-k sum via radix select + fused finalize (ticket: last block
// sums the B-length partial arrays and writes both outputs).
__global__ void __launch_bounds__(1024) k_hardneg(const float* __restrict__ mine,
                                                  const int* __restrict__ npA,
                                                  const double* __restrict__ plA,
                                                  const double* __restrict__ pcA,
                                                  double* __restrict__ acc,
                                                  u32* __restrict__ ticket,
                                                  float* __restrict__ out) {
    const int b = blockIdx.x;
    const int tid = threadIdx.x;
    const int lane = tid & 63, wave = tid >> 6;
    __shared__ float s_mine[P];
    __shared__ u32 s_hist[256];
    __shared__ u32 s_sel[2];
    __shared__ double s_red[16];
    __shared__ int s_k, s_tp;

    if (tid == 0) {
        int tp = 0;
        for (int i = 0; i < B; i++) tp += npA[i];
        int np = npA[b];
        int k = 3 * np;
        int cap = P - tp - 1;
        if (cap < k) k = cap;
        s_k = k;
        s_tp = tp;
    }
    __syncthreads();
    const int k = s_k;

    if (k > 0) {
        for (int i = tid; i < P; i += 1024) s_mine[i] = mine[(size_t)b * P + i];
        if (tid == 0) { s_sel[0] = 0u; s_sel[1] = (u32)k; }
        __syncthreads();

        for (int shift = 24; shift >= 0; shift -= 8) {
            if (tid < 256) s_hist[tid] = 0u;
            __syncthreads();
            u32 prefix = s_sel[0];
            u32 kr = s_sel[1];
            u32 himask = (shift == 24) ? 0u : (0xFFFFFFFFu << (shift + 8));
            for (int i = tid; i < P; i += 1024) {
                u32 v = __float_as_uint(s_mine[i]);
                if ((v & himask) == prefix) atomicAdd(&s_hist[(v >> shift) & 255u], 1u);
            }
            __syncthreads();
            if (tid < 64) {
                const int L = tid;
                const int btop = 255 - 4 * L;
                u32 h0 = s_hist[btop], h1 = s_hist[btop - 1], h2 = s_hist[btop - 2], h3 = s_hist[btop - 3];
                u32 g4 = h0 + h1 + h2 + h3;
                u32 x = g4;
#pragma unroll
                for (int off = 1; off < 64; off <<= 1) {
                    u32 v = __shfl_up(x, off, 64);
                    if (L >= off) x += v;
                }
                u32 excl = x - g4;
                if (excl < kr && excl + g4 >= kr) {
                    u32 c = excl; int chosen = btop; u32 kloc = kr;
                    u32 nc;
                    nc = c + h0; if (c < kr && nc >= kr) { chosen = btop;     kloc = kr - c; } c = nc;
                    nc = c + h1; if (c < kr && nc >= kr) { chosen = btop - 1; kloc = kr - c; } c = nc;
                    nc = c + h2; if (c < kr && nc >= kr) { chosen = btop - 2; kloc = kr - c; } c = nc;
                    nc = c + h3; if (c < kr && nc >= kr) { chosen = btop - 3; kloc = kr - c; } c = nc;
                    s_sel[0] = prefix | ((u32)chosen << shift);
                    s_sel[1] = kloc;
                }
            }
            __syncthreads();
        }

        u32 tbits = s_sel[0];
        u32 kr = s_sel[1];
        float T = __uint_as_float(tbits);

        double sd = 0.0;
        for (int i = tid; i < P; i += 1024) {
            u32 v = __float_as_uint(s_mine[i]);
            if (v > tbits) sd += (double)s_mine[i];
        }
#pragma unroll
        for (int off = 32; off > 0; off >>= 1) sd += __shfl_xor(sd, off, 64);
        if (lane == 0) s_red[wave] = sd;
        __syncthreads();
        if (tid == 0) {
            double tt = 0.0;
#pragma unroll
            for (int w = 0; w < 16; w++) tt += s_red[w];
            atomicAdd(&acc[0], tt + (double)kr * (double)T);
        }
    }

    // fused finalize
    __threadfence();
    __syncthreads();
    __shared__ int s_last;
    if (tid == 0) s_last = (atomicAdd(ticket, 1u) == B - 1) ? 1 : 0;
    __syncthreads();
    if (s_last && tid == 0) {
        double al = 0.0, ac = 0.0;
        for (int i = 0; i < B; i++) { al += plA[i]; ac += pcA[i]; }
        __threadfence();
        double ag = atomicAdd(&acc[0], 0.0);
        double n = (double)s_tp;
        out[0] = (float)(al / n);
        out[1] = (float)((ac + ag) / n);
    }
}

extern "C" void kernel_launch(void* const* d_in, const int* in_sizes, int n_in,
                              void* d_out, int out_size, void* d_ws, size_t ws_size,
                              hipStream_t stream) {
    const float* loc_preds = (const float*)d_in[0];
    const float* scores    = (const float*)d_in[1];
    const float* gt        = (const float*)d_in[2];
    const float* priors    = (const float*)d_in[3];

    char* ws = (char*)d_ws;
    u64* bk      = (u64*)ws;                  // [0, 131072)        B*O*NB1 u64
    int* npA     = (int*)(ws + 131072);       // [131072, 131584)   B int
    double* plA  = (double*)(ws + 131584);    // [131584, 132608)   B dbl
    double* pcA  = (double*)(ws + 132608);    // [132608, 133632)   B dbl
    double* acc  = (double*)(ws + 133632);    // [133632, 133640)
    u32* ticket  = (u32*)(ws + 133640);       // [133640, 133644)
    u8* bidx     = (u8*)(ws + 133648);        // [133648, 1251344)  B*P u8
    float* mine  = (float*)(ws + 1251360);    // B*P*4 (16B-aligned)

    // no memset needed: every ws slot consumed is plainly overwritten each call

    k_main<<<dim3(SCORE_BLKS + P1_BLKS), dim3(256), 0, stream>>>(
        gt, priors, scores, bk, bidx, mine);
    k_fix<<<dim3(B), dim3(256), 0, stream>>>(
        gt, priors, loc_preds, scores, bk, bidx, mine, npA, plA, pcA, acc, ticket);
    k_hardneg<<<dim3(B), dim3(1024), 0, stream>>>(mine, npA, plA, pcA, acc, ticket,
                                                  (float*)d_out);
}

// Round 18
// 86.021 us; speedup vs baseline: 1.6993x; 1.6993x over previous
//
#include <hip/hip_runtime.h>
#include <cstdint>
#include <cstddef>

#define B 128
#define P 8732
#define NC 21
#define O 16
#define THRESH 0.5f
#define NB1 8      // pass1 blocks per image
#define NBX2 6     // pass2 blocks per image
#define BPB 1456   // priors per pass2 block
#define WPW 364    // priors per wave
#define NPART (B * NBX2)
#define SLABF 1536 // padded slab floats: 6 DMA instrs x 64 lanes x 4 floats

typedef unsigned long long u64;
typedef unsigned int u32;
typedef unsigned char u8;

__device__ __forceinline__ float iou_pt(float a0, float a1, float a2, float a3,
                                        float b0, float b1, float b2, float b3) {
    float ltx = fmaxf(a0, b0), lty = fmaxf(a1, b1);
    float rbx = fminf(a2, b2), rby = fminf(a3, b3);
    float wx = fmaxf(rbx - ltx, 0.0f), wy = fmaxf(rby - lty, 0.0f);
    float inter = wx * wy;
    float aa = (a2 - a0) * (a3 - a1);
    float ab = (b2 - b0) * (b3 - b1);
    return inter / (aa + ab - inter);
}

// Pass 1: per-object best-prior partial max (plain stores) AND per-prior
// packed best-truth byte: idx | (ov>=THRESH ? 0x80 : 0). Block (0,0) also
// zeroes the hardneg accumulator + ticket (visible at kernel boundary).
__global__ void __launch_bounds__(256) k_pass1(const float* __restrict__ gt,
                                               const float* __restrict__ priors,
                                               u64* __restrict__ bk,
                                               u8* __restrict__ bidx,
                                               double* __restrict__ acc,
                                               u32* __restrict__ ticket) {
    const int b = blockIdx.y;
    __shared__ float s_gt[O * 4];
    __shared__ u64 s_wk[4][O];
    const int tid = threadIdx.x;
    const int wave = tid >> 6, lane = tid & 63;
    if (blockIdx.x == 0 && b == 0 && tid == 0) { acc[0] = 0.0; *ticket = 0u; }
    if (tid < O * 4) {
        int o = tid >> 2, c = tid & 3;
        s_gt[tid] = gt[(b * O + o) * 5 + c];
    }
    __syncthreads();

    u64 lk[O];
#pragma unroll
    for (int o = 0; o < O; o++) lk[o] = 0ull;

    for (int p = blockIdx.x * 256 + tid; p < P; p += NB1 * 256) {
        float4 pr = reinterpret_cast<const float4*>(priors)[p];
        float b0 = pr.x - pr.z * 0.5f, b1 = pr.y - pr.w * 0.5f;
        float b2 = pr.x + pr.z * 0.5f, b3 = pr.y + pr.w * 0.5f;
        float bov = -1.0f; int bo = 0;
#pragma unroll
        for (int o = 0; o < O; o++) {
            float v = iou_pt(s_gt[o * 4 + 0], s_gt[o * 4 + 1], s_gt[o * 4 + 2], s_gt[o * 4 + 3],
                             b0, b1, b2, b3);
            u64 key = ((u64)__float_as_uint(v) << 32) | (u64)(0xFFFFFFFFu - (u32)p);
            lk[o] = (key > lk[o]) ? key : lk[o];
            if (v > bov) { bov = v; bo = o; }   // first occurrence on tie
        }
        bidx[(size_t)b * P + p] = (u8)(bo | ((bov >= THRESH) ? 0x80 : 0));
    }

#pragma unroll
    for (int o = 0; o < O; o++) {
        u64 k = lk[o];
#pragma unroll
        for (int off = 32; off > 0; off >>= 1) {
            u64 other = (u64)__shfl_xor((long long)k, off, 64);
            k = (other > k) ? other : k;
        }
        if (lane == 0) s_wk[wave][o] = k;
    }
    __syncthreads();
    if (tid < O) {
        u64 k = s_wk[0][tid];
#pragma unroll
        for (int w = 1; w < 4; w++) { u64 v = s_wk[w][tid]; k = (v > k) ? v : k; }
        bk[((size_t)b * O + tid) * NB1 + blockIdx.x] = k;
    }
}

// Stage one 64-prior score chunk into a wave-private padded LDS slab via
// global_load_lds DMA. All 6 instructions always issue with all lanes
// (vmcnt increments exact). LDS dest = base+lane*16 unconditionally ->
// slab padded to 6*1024 B; clamped global sources stay in-bounds; pad never
// read.
__device__ __forceinline__ void stage64(const float* __restrict__ gsrc,
                                        float* lds, int nf4, int lane) {
    const char* src = (const char*)gsrc;
    char* dst = (char*)lds;
#pragma unroll
    for (int i = 0; i < 6; i++) {
        int idx = i * 64 + lane;
        if (idx >= nf4) idx = nf4 - 1;
        __builtin_amdgcn_global_load_lds(
            (const __attribute__((address_space(1))) u32*)(src + (size_t)idx * 16),
            (__attribute__((address_space(3))) u32*)(dst + i * 1024),
            16, 0, 0);
    }
}

// Pass 2: wave-synchronous double-buffered DMA pipeline (R12 structure,
// proven 43.5us). Coalesced score supply, counted vmcnt(6). No atomics.
__global__ void __launch_bounds__(256) k_pass2(const float* __restrict__ gt,
                                               const float* __restrict__ priors,
                                               const u64* __restrict__ bk,
                                               const u8* __restrict__ bidx,
                                               const float* __restrict__ loc_preds,
                                               const float* __restrict__ scores,
                                               float* __restrict__ mine,
                                               double* __restrict__ pl,
                                               double* __restrict__ pc,
                                               int* __restrict__ pn) {
    const int b = blockIdx.y;
    const int tid = threadIdx.x;
    const int wave = tid >> 6, lane = tid & 63;
    __shared__ float s_slab[4][2][SLABF];   // 4 waves x 2 bufs x padded slab
    __shared__ float s_gt[O * 5];
    __shared__ int s_bp[O];

    if (tid < O * 5) s_gt[tid] = gt[b * O * 5 + tid];
    if (tid < O) {
        u64 k = bk[((size_t)b * O + tid) * NB1];
#pragma unroll
        for (int i = 1; i < NB1; i++) {
            u64 v = bk[((size_t)b * O + tid) * NB1 + i];
            k = (v > k) ? v : k;
        }
        s_bp[tid] = (int)(0xFFFFFFFFu - (u32)(k & 0xFFFFFFFFull));
    }
    __syncthreads();

    const int wbase = blockIdx.x * BPB + wave * WPW;
    int wp = P - wbase; if (wp > WPW) wp = WPW;
    const int nchunk = (wp > 0) ? ((wp + 63) >> 6) : 0;

    float l_loc = 0.f, l_ce = 0.f;
    int l_np = 0;

    if (nchunk > 0) {
        {
            int nv0 = wp < 64 ? wp : 64;
            stage64(scores + ((size_t)b * P + wbase) * NC,
                    &s_slab[wave][0][0], nv0 * 21 / 4, lane);
        }
        for (int c = 0; c < nchunk; ++c) {
            const int base = wbase + c * 64;
            int nv = wp - c * 64; if (nv > 64) nv = 64;

            if (c + 1 < nchunk) {
                int nv2 = wp - (c + 1) * 64; if (nv2 > 64) nv2 = 64;
                asm volatile("s_waitcnt lgkmcnt(0)" ::: "memory");  // drain reads of buf being overwritten
                stage64(scores + ((size_t)b * P + base + 64) * NC,
                        &s_slab[wave][(c + 1) & 1][0], nv2 * 21 / 4, lane);
                asm volatile("s_waitcnt vmcnt(6)" ::: "memory");    // chunk c landed; c+1 stays in flight
            } else {
                asm volatile("s_waitcnt vmcnt(0)" ::: "memory");
            }
            __builtin_amdgcn_sched_barrier(0);

            if (lane < nv) {
                const int p = base + lane;
                const float* fsl = &s_slab[wave][c & 1][lane * NC];
                float fs[NC];
#pragma unroll
                for (int cc = 0; cc < NC; cc++) fs[cc] = fsl[cc];   // stride-21: 2-way bank = free

                int e = (int)bidx[(size_t)b * P + p];
                int best_idx = e & 0x3F;
                bool matched = (e & 0x80) != 0;
#pragma unroll
                for (int o = 0; o < O; o++) {
                    if (s_bp[o] == p) { best_idx = o; matched = true; }   // last wins
                }
                int cls = matched ? (int)s_gt[best_idx * 5 + 4] : 0;

                float mx = fs[0];
#pragma unroll
                for (int cc = 1; cc < NC; cc++) mx = fmaxf(mx, fs[cc]);
                float se = 0.0f;
#pragma unroll
                for (int cc = 0; cc < NC; cc++) se += __expf(fs[cc] - mx);
                float lse = mx + __logf(se);
                float g = fs[0];
#pragma unroll
                for (int cc = 1; cc < NC; cc++) g = (cc == cls) ? fs[cc] : g;
                float ce = lse - g;

                mine[(size_t)b * P + p] = matched ? 0.0f : ce;

                if (matched) {   // matched <=> positive (labels >= 1)
                    l_np++;
                    l_ce += ce;
                    float4 pr = reinterpret_cast<const float4*>(priors)[p];
                    float m0 = s_gt[best_idx * 5 + 0], m1 = s_gt[best_idx * 5 + 1];
                    float m2 = s_gt[best_idx * 5 + 2], m3 = s_gt[best_idx * 5 + 3];
                    float tx = ((m0 + m2) * 0.5f - pr.x) / (0.1f * pr.z);
                    float ty = ((m1 + m3) * 0.5f - pr.y) / (0.1f * pr.w);
                    float tw = __logf((m2 - m0) / pr.z) * 5.0f;
                    float th = __logf((m3 - m1) / pr.w) * 5.0f;
                    float4 lp = reinterpret_cast<const float4*>(loc_preds)[(size_t)b * P + p];
                    float d0 = fabsf(lp.x - tx), d1 = fabsf(lp.y - ty);
                    float d2 = fabsf(lp.z - tw), d3 = fabsf(lp.w - th);
                    float s0 = d0 < 1.0f ? 0.5f * d0 * d0 : d0 - 0.5f;
                    float s1 = d1 < 1.0f ? 0.5f * d1 * d1 : d1 - 0.5f;
                    float s2 = d2 < 1.0f ? 0.5f * d2 * d2 : d2 - 0.5f;
                    float s3 = d3 < 1.0f ? 0.5f * d3 * d3 : d3 - 0.5f;
                    l_loc += (s0 + s1) + (s2 + s3);
                }
            }
        }
    }

    // wave shuffle reductions -> plain partial stores
#pragma unroll
    for (int off = 32; off > 0; off >>= 1) {
        l_loc += __shfl_xor(l_loc, off, 64);
        l_ce  += __shfl_xor(l_ce, off, 64);
        l_np  += __shfl_xor(l_np, off, 64);
    }
    __shared__ double s_loc[4], s_ce[4];
    __shared__ int s_np[4];
    if (lane == 0) { s_loc[wave] = (double)l_loc; s_ce[wave] = (double)l_ce; s_np[wave] = l_np; }
    __syncthreads();
    if (tid == 0) {
        int q = b * NBX2 + blockIdx.x;
        pl[q] = (s_loc[0] + s_loc[1]) + (s_loc[2] + s_loc[3]);
        pc[q] = (s_ce[0] + s_ce[1]) + (s_ce[2] + s_ce[3]);
        pn[q] = s_np[0] + s_np[1] + s_np[2] + s_np[3];
    }
}

// Hard-negative top-k sum with fused finalize (R14-proven ticket pattern).
// Each block self-computes total_pos + its k, radix-selects, adds its
// neg-sum to acc[0] (128 atomics total); the last block sums pl/pc and
// writes both outputs.
__global__ void __launch_bounds__(1024) k_hardneg(const float* __restrict__ mine,
                                                  const double* __restrict__ pl,
                                                  const double* __restrict__ pc,
                                                  const int* __restrict__ pn,
                                                  double* __restrict__ acc,
                                                  u32* __restrict__ ticket,
                                                  float* __restrict__ out) {
    const int b = blockIdx.x;
    const int tid = threadIdx.x;
    const int lane = tid & 63, wave = tid >> 6;
    __shared__ float s_mine[P];
    __shared__ u32 s_hist[256];
    __shared__ u32 s_sel[2];
    __shared__ double s_red[16];
    __shared__ int s_ti[16];
    __shared__ int s_npx[NBX2];
    __shared__ int s_k, s_tp;

    {
        int t = 0;
        for (int i = tid; i < NPART; i += 1024) t += pn[i];
#pragma unroll
        for (int off = 32; off > 0; off >>= 1) t += __shfl_xor(t, off, 64);
        if (lane == 0) s_ti[wave] = t;
    }
    if (tid < NBX2) s_npx[tid] = pn[b * NBX2 + tid];
    __syncthreads();
    if (tid == 0) {
        int tp = 0;
#pragma unroll
        for (int w = 0; w < 16; w++) tp += s_ti[w];
        int np = 0;
#pragma unroll
        for (int x = 0; x < NBX2; x++) np += s_npx[x];
        int k = 3 * np;
        int cap = P - tp - 1;
        if (cap < k) k = cap;
        s_k = k;
        s_tp = tp;
    }
    __syncthreads();
    const int k = s_k;

    if (k > 0) {
        for (int i = tid; i < P; i += 1024) s_mine[i] = mine[(size_t)b * P + i];
        if (tid == 0) { s_sel[0] = 0u; s_sel[1] = (u32)k; }
        __syncthreads();

        for (int shift = 24; shift >= 0; shift -= 8) {
            if (tid < 256) s_hist[tid] = 0u;
            __syncthreads();
            u32 prefix = s_sel[0];
            u32 kr = s_sel[1];
            u32 himask = (shift == 24) ? 0u : (0xFFFFFFFFu << (shift + 8));
            for (int i = tid; i < P; i += 1024) {
                u32 v = __float_as_uint(s_mine[i]);
                if ((v & himask) == prefix) atomicAdd(&s_hist[(v >> shift) & 255u], 1u);
            }
            __syncthreads();
            if (tid < 64) {
                const int L = tid;
                const int btop = 255 - 4 * L;
                u32 h0 = s_hist[btop], h1 = s_hist[btop - 1], h2 = s_hist[btop - 2], h3 = s_hist[btop - 3];
                u32 g4 = h0 + h1 + h2 + h3;
                u32 x = g4;
#pragma unroll
                for (int off = 1; off < 64; off <<= 1) {
                    u32 v = __shfl_up(x, off, 64);
                    if (L >= off) x += v;
                }
                u32 excl = x - g4;
                if (excl < kr && excl + g4 >= kr) {
                    u32 c = excl; int chosen = btop; u32 kloc = kr;
                    u32 nc;
                    nc = c + h0; if (c < kr && nc >= kr) { chosen = btop;     kloc = kr - c; } c = nc;
                    nc = c + h1; if (c < kr && nc >= kr) { chosen = btop - 1; kloc = kr - c; } c = nc;
                    nc = c + h2; if (c < kr && nc >= kr) { chosen = btop - 2; kloc = kr - c; } c = nc;
                    nc = c + h3; if (c < kr && nc >= kr) { chosen = btop - 3; kloc = kr - c; } c = nc;
                    s_sel[0] = prefix | ((u32)chosen << shift);
                    s_sel[1] = kloc;
                }
            }
            __syncthreads();
        }

        u32 tbits = s_sel[0];
        u32 kr = s_sel[1];
        float T = __uint_as_float(tbits);

        double sd = 0.0;
        for (int i = tid; i < P; i += 1024) {
            u32 v = __float_as_uint(s_mine[i]);
            if (v > tbits) sd += (double)s_mine[i];
        }
#pragma unroll
        for (int off = 32; off > 0; off >>= 1) sd += __shfl_xor(sd, off, 64);
        if (lane == 0) s_red[wave] = sd;
        __syncthreads();
        if (tid == 0) {
            double tt = 0.0;
#pragma unroll
            for (int w = 0; w < 16; w++) tt += s_red[w];
            atomicAdd(&acc[0], tt + (double)kr * (double)T);
        }
    }

    // fused finalize: last block to arrive writes the outputs
    __threadfence();
    __syncthreads();
    __shared__ int s_last;
    if (tid == 0) s_last = (atomicAdd(ticket, 1u) == B - 1) ? 1 : 0;
    __syncthreads();
    if (s_last) {
        __shared__ double f_l[16], f_c[16];
        double tl = 0.0, tc = 0.0;
        for (int i = tid; i < NPART; i += 1024) { tl += pl[i]; tc += pc[i]; }
#pragma unroll
        for (int off = 32; off > 0; off >>= 1) {
            tl += __shfl_xor(tl, off, 64);
            tc += __shfl_xor(tc, off, 64);
        }
        if (lane == 0) { f_l[wave] = tl; f_c[wave] = tc; }
        __syncthreads();
        if (tid == 0) {
            double al = 0.0, ac = 0.0;
#pragma unroll
            for (int w = 0; w < 16; w++) { al += f_l[w]; ac += f_c[w]; }
            __threadfence();
            double ag = atomicAdd(&acc[0], 0.0);
            double n = (double)s_tp;
            out[0] = (float)(al / n);
            out[1] = (float)((ac + ag) / n);
        }
    }
}

extern "C" void kernel_launch(void* const* d_in, const int* in_sizes, int n_in,
                              void* d_out, int out_size, void* d_ws, size_t ws_size,
                              hipStream_t stream) {
    const float* loc_preds = (const float*)d_in[0];
    const float* scores    = (const float*)d_in[1];
    const float* gt        = (const float*)d_in[2];
    const float* priors    = (const float*)d_in[3];

    char* ws = (char*)d_ws;
    u64* bk      = (u64*)ws;                  // [0, 131072)        B*O*NB1 u64
    double* pl   = (double*)(ws + 131072);    // [131072, 137216)   NPART=768 dbl
    double* pc   = (double*)(ws + 137216);    // [137216, 143360)
    int* pn      = (int*)(ws + 143360);       // [143360, 146432)
    double* acc  = (double*)(ws + 146432);    // [146432, 146440)   neg-sum
    u32* ticket  = (u32*)(ws + 146440);       // [146440, 146444)
    u8* bidx     = (u8*)(ws + 146448);        // [146448, 1264144)  B*P u8
    float* mine  = (float*)(ws + 1264160);    // B*P*4 (16B-aligned)

    // no memset needed: acc/ticket zeroed by k_pass1; all else plainly overwritten

    k_pass1<<<dim3(NB1, B), dim3(256), 0, stream>>>(gt, priors, bk, bidx, acc, ticket);
    k_pass2<<<dim3(NBX2, B), dim3(256), 0, stream>>>(
        gt, priors, bk, bidx, loc_preds, scores, mine, pl, pc, pn);
    k_hardneg<<<dim3(B), dim3(1024), 0, stream>>>(mine, pl, pc, pn, acc, ticket,
                                                  (float*)d_out);
}

// Round 19
// 58.190 us; speedup vs baseline: 2.5121x; 1.4783x over previous
//
#include <hip/hip_runtime.h>
#include <cstdint>
#include <cstddef>

#define B 128
#define P 8732
#define NC 21
#define O 16
#define THRESH 0.5f
#define NB1 8      // pass1 blocks per image
#define NBX2 6     // pass2 blocks per image
#define BPB 1456   // priors per pass2 block
#define WPW 364    // priors per wave
#define NPART (B * NBX2)
#define SLABF 1536 // padded slab floats: 6 DMA instrs x 64 lanes x 4 floats

typedef unsigned long long u64;
typedef unsigned int u32;
typedef unsigned char u8;

__device__ __forceinline__ float iou_pt(float a0, float a1, float a2, float a3,
                                        float b0, float b1, float b2, float b3) {
    float ltx = fmaxf(a0, b0), lty = fmaxf(a1, b1);
    float rbx = fminf(a2, b2), rby = fminf(a3, b3);
    float wx = fmaxf(rbx - ltx, 0.0f), wy = fmaxf(rby - lty, 0.0f);
    float inter = wx * wy;
    float aa = (a2 - a0) * (a3 - a1);
    float ab = (b2 - b0) * (b3 - b1);
    return inter / (aa + ab - inter);
}

// Pass 1: per-object best-prior partial max (plain stores) AND per-prior
// packed best-truth byte: idx | (ov>=THRESH ? 0x80 : 0).
__global__ void __launch_bounds__(256) k_pass1(const float* __restrict__ gt,
                                               const float* __restrict__ priors,
                                               u64* __restrict__ bk,
                                               u8* __restrict__ bidx) {
    const int b = blockIdx.y;
    __shared__ float s_gt[O * 4];
    __shared__ u64 s_wk[4][O];
    const int tid = threadIdx.x;
    const int wave = tid >> 6, lane = tid & 63;
    if (tid < O * 4) {
        int o = tid >> 2, c = tid & 3;
        s_gt[tid] = gt[(b * O + o) * 5 + c];
    }
    __syncthreads();

    u64 lk[O];
#pragma unroll
    for (int o = 0; o < O; o++) lk[o] = 0ull;

    for (int p = blockIdx.x * 256 + tid; p < P; p += NB1 * 256) {
        float4 pr = reinterpret_cast<const float4*>(priors)[p];
        float b0 = pr.x - pr.z * 0.5f, b1 = pr.y - pr.w * 0.5f;
        float b2 = pr.x + pr.z * 0.5f, b3 = pr.y + pr.w * 0.5f;
        float bov = -1.0f; int bo = 0;
#pragma unroll
        for (int o = 0; o < O; o++) {
            float v = iou_pt(s_gt[o * 4 + 0], s_gt[o * 4 + 1], s_gt[o * 4 + 2], s_gt[o * 4 + 3],
                             b0, b1, b2, b3);
            u64 key = ((u64)__float_as_uint(v) << 32) | (u64)(0xFFFFFFFFu - (u32)p);
            lk[o] = (key > lk[o]) ? key : lk[o];
            if (v > bov) { bov = v; bo = o; }   // first occurrence on tie
        }
        bidx[(size_t)b * P + p] = (u8)(bo | ((bov >= THRESH) ? 0x80 : 0));
    }

#pragma unroll
    for (int o = 0; o < O; o++) {
        u64 k = lk[o];
#pragma unroll
        for (int off = 32; off > 0; off >>= 1) {
            u64 other = (u64)__shfl_xor((long long)k, off, 64);
            k = (other > k) ? other : k;
        }
        if (lane == 0) s_wk[wave][o] = k;
    }
    __syncthreads();
    if (tid < O) {
        u64 k = s_wk[0][tid];
#pragma unroll
        for (int w = 1; w < 4; w++) { u64 v = s_wk[w][tid]; k = (v > k) ? v : k; }
        bk[((size_t)b * O + tid) * NB1 + blockIdx.x] = k;
    }
}

// Stage one 64-prior score chunk into a wave-private padded LDS slab via
// global_load_lds DMA. All 6 instructions always issue with all lanes
// (vmcnt increments exact). LDS dest = base+lane*16 unconditionally ->
// slab padded to 6*1024 B; clamped global sources stay in-bounds; pad never
// read.
__device__ __forceinline__ void stage64(const float* __restrict__ gsrc,
                                        float* lds, int nf4, int lane) {
    const char* src = (const char*)gsrc;
    char* dst = (char*)lds;
#pragma unroll
    for (int i = 0; i < 6; i++) {
        int idx = i * 64 + lane;
        if (idx >= nf4) idx = nf4 - 1;
        __builtin_amdgcn_global_load_lds(
            (const __attribute__((address_space(1))) u32*)(src + (size_t)idx * 16),
            (__attribute__((address_space(3))) u32*)(dst + i * 1024),
            16, 0, 0);
    }
}

// Pass 2: wave-synchronous double-buffered DMA pipeline. Coalesced score
// supply (16 lines per vmem instr, no VGPR round-trip), counted vmcnt(6) so
// the next chunk's loads fly under the current chunk's compute. No atomics.
__global__ void __launch_bounds__(256) k_pass2(const float* __restrict__ gt,
                                               const float* __restrict__ priors,
                                               const u64* __restrict__ bk,
                                               const u8* __restrict__ bidx,
                                               const float* __restrict__ loc_preds,
                                               const float* __restrict__ scores,
                                               float* __restrict__ mine,
                                               double* __restrict__ pl,
                                               double* __restrict__ pc,
                                               int* __restrict__ pn) {
    const int b = blockIdx.y;
    const int tid = threadIdx.x;
    const int wave = tid >> 6, lane = tid & 63;
    __shared__ float s_slab[4][2][SLABF];   // 4 waves x 2 bufs x padded slab
    __shared__ float s_gt[O * 5];
    __shared__ int s_bp[O];

    if (tid < O * 5) s_gt[tid] = gt[b * O * 5 + tid];
    if (tid < O) {
        u64 k = bk[((size_t)b * O + tid) * NB1];
#pragma unroll
        for (int i = 1; i < NB1; i++) {
            u64 v = bk[((size_t)b * O + tid) * NB1 + i];
            k = (v > k) ? v : k;
        }
        s_bp[tid] = (int)(0xFFFFFFFFu - (u32)(k & 0xFFFFFFFFull));
    }
    __syncthreads();

    const int wbase = blockIdx.x * BPB + wave * WPW;
    int wp = P - wbase; if (wp > WPW) wp = WPW;
    const int nchunk = (wp > 0) ? ((wp + 63) >> 6) : 0;

    float l_loc = 0.f, l_ce = 0.f;
    int l_np = 0;

    if (nchunk > 0) {
        {
            int nv0 = wp < 64 ? wp : 64;
            stage64(scores + ((size_t)b * P + wbase) * NC,
                    &s_slab[wave][0][0], nv0 * 21 / 4, lane);
        }
        for (int c = 0; c < nchunk; ++c) {
            const int base = wbase + c * 64;
            int nv = wp - c * 64; if (nv > 64) nv = 64;

            if (c + 1 < nchunk) {
                int nv2 = wp - (c + 1) * 64; if (nv2 > 64) nv2 = 64;
                asm volatile("s_waitcnt lgkmcnt(0)" ::: "memory");  // drain reads of buf being overwritten
                stage64(scores + ((size_t)b * P + base + 64) * NC,
                        &s_slab[wave][(c + 1) & 1][0], nv2 * 21 / 4, lane);
                asm volatile("s_waitcnt vmcnt(6)" ::: "memory");    // chunk c landed; c+1 stays in flight
            } else {
                asm volatile("s_waitcnt vmcnt(0)" ::: "memory");
            }
            __builtin_amdgcn_sched_barrier(0);

            if (lane < nv) {
                const int p = base + lane;
                const float* fsl = &s_slab[wave][c & 1][lane * NC];
                float fs[NC];
#pragma unroll
                for (int cc = 0; cc < NC; cc++) fs[cc] = fsl[cc];   // stride-21: 2-way bank = free

                int e = (int)bidx[(size_t)b * P + p];
                int best_idx = e & 0x3F;
                bool matched = (e & 0x80) != 0;
#pragma unroll
                for (int o = 0; o < O; o++) {
                    if (s_bp[o] == p) { best_idx = o; matched = true; }   // last wins
                }
                int cls = matched ? (int)s_gt[best_idx * 5 + 4] : 0;

                float mx = fs[0];
#pragma unroll
                for (int cc = 1; cc < NC; cc++) mx = fmaxf(mx, fs[cc]);
                float se = 0.0f;
#pragma unroll
                for (int cc = 0; cc < NC; cc++) se += __expf(fs[cc] - mx);
                float lse = mx + __logf(se);
                float g = fs[0];
#pragma unroll
                for (int cc = 1; cc < NC; cc++) g = (cc == cls) ? fs[cc] : g;
                float ce = lse - g;

                mine[(size_t)b * P + p] = matched ? 0.0f : ce;

                if (matched) {   // matched <=> positive (labels >= 1)
                    l_np++;
                    l_ce += ce;
                    float4 pr = reinterpret_cast<const float4*>(priors)[p];
                    float m0 = s_gt[best_idx * 5 + 0], m1 = s_gt[best_idx * 5 + 1];
                    float m2 = s_gt[best_idx * 5 + 2], m3 = s_gt[best_idx * 5 + 3];
                    float tx = ((m0 + m2) * 0.5f - pr.x) / (0.1f * pr.z);
                    float ty = ((m1 + m3) * 0.5f - pr.y) / (0.1f * pr.w);
                    float tw = __logf((m2 - m0) / pr.z) * 5.0f;
                    float th = __logf((m3 - m1) / pr.w) * 5.0f;
                    float4 lp = reinterpret_cast<const float4*>(loc_preds)[(size_t)b * P + p];
                    float d0 = fabsf(lp.x - tx), d1 = fabsf(lp.y - ty);
                    float d2 = fabsf(lp.z - tw), d3 = fabsf(lp.w - th);
                    float s0 = d0 < 1.0f ? 0.5f * d0 * d0 : d0 - 0.5f;
                    float s1 = d1 < 1.0f ? 0.5f * d1 * d1 : d1 - 0.5f;
                    float s2 = d2 < 1.0f ? 0.5f * d2 * d2 : d2 - 0.5f;
                    float s3 = d3 < 1.0f ? 0.5f * d3 * d3 : d3 - 0.5f;
                    l_loc += (s0 + s1) + (s2 + s3);
                }
            }
        }
    }

    // wave shuffle reductions -> plain partial stores
#pragma unroll
    for (int off = 32; off > 0; off >>= 1) {
        l_loc += __shfl_xor(l_loc, off, 64);
        l_ce  += __shfl_xor(l_ce, off, 64);
        l_np  += __shfl_xor(l_np, off, 64);
    }
    __shared__ double s_loc[4], s_ce[4];
    __shared__ int s_np[4];
    if (lane == 0) { s_loc[wave] = (double)l_loc; s_ce[wave] = (double)l_ce; s_np[wave] = l_np; }
    __syncthreads();
    if (tid == 0) {
        int q = b * NBX2 + blockIdx.x;
        pl[q] = (s_loc[0] + s_loc[1]) + (s_loc[2] + s_loc[3]);
        pc[q] = (s_ce[0] + s_ce[1]) + (s_ce[2] + s_ce[3]);
        pn[q] = s_np[0] + s_np[1] + s_np[2] + s_np[3];
    }
}

// Hard-negative top-k sum; self-computes total_pos; plain stores; no atomics,
// no device fences (cross-block reduction via kernel boundary -- cheaper than
// ticket+threadfence on CDNA4's non-coherent per-XCD L2s, cf. R18's +28us).
__global__ void __launch_bounds__(1024) k_hardneg(const float* __restrict__ mine,
                                                  const int* __restrict__ pn,
                                                  double* __restrict__ pneg) {
    const int b = blockIdx.x;
    const int tid = threadIdx.x;
    const int lane = tid & 63, wave = tid >> 6;
    __shared__ float s_mine[P];
    __shared__ u32 s_hist[256];
    __shared__ u32 s_sel[2];
    __shared__ double s_red[16];
    __shared__ int s_ti[16];
    __shared__ int s_npx[NBX2];
    __shared__ int s_k;

    {
        int t = 0;
        for (int i = tid; i < NPART; i += 1024) t += pn[i];
#pragma unroll
        for (int off = 32; off > 0; off >>= 1) t += __shfl_xor(t, off, 64);
        if (lane == 0) s_ti[wave] = t;
    }
    if (tid < NBX2) s_npx[tid] = pn[b * NBX2 + tid];
    __syncthreads();
    if (tid == 0) {
        int tp = 0;
#pragma unroll
        for (int w = 0; w < 16; w++) tp += s_ti[w];
        int np = 0;
#pragma unroll
        for (int x = 0; x < NBX2; x++) np += s_npx[x];
        int k = 3 * np;
        int cap = P - tp - 1;
        if (cap < k) k = cap;
        s_k = k;
    }
    __syncthreads();
    const int k = s_k;

    if (k <= 0) {
        if (tid == 0) pneg[b] = 0.0;
        return;
    }

    for (int i = tid; i < P; i += 1024) s_mine[i] = mine[(size_t)b * P + i];
    if (tid == 0) { s_sel[0] = 0u; s_sel[1] = (u32)k; }
    __syncthreads();

    for (int shift = 24; shift >= 0; shift -= 8) {
        if (tid < 256) s_hist[tid] = 0u;
        __syncthreads();
        u32 prefix = s_sel[0];
        u32 kr = s_sel[1];
        u32 himask = (shift == 24) ? 0u : (0xFFFFFFFFu << (shift + 8));
        for (int i = tid; i < P; i += 1024) {
            u32 v = __float_as_uint(s_mine[i]);
            if ((v & himask) == prefix) atomicAdd(&s_hist[(v >> shift) & 255u], 1u);
        }
        __syncthreads();
        if (tid < 64) {
            const int L = tid;
            const int btop = 255 - 4 * L;
            u32 h0 = s_hist[btop], h1 = s_hist[btop - 1], h2 = s_hist[btop - 2], h3 = s_hist[btop - 3];
            u32 g4 = h0 + h1 + h2 + h3;
            u32 x = g4;
#pragma unroll
            for (int off = 1; off < 64; off <<= 1) {
                u32 v = __shfl_up(x, off, 64);
                if (L >= off) x += v;
            }
            u32 excl = x - g4;
            if (excl < kr && excl + g4 >= kr) {
                u32 c = excl; int chosen = btop; u32 kloc = kr;
                u32 nc;
                nc = c + h0; if (c < kr && nc >= kr) { chosen = btop;     kloc = kr - c; } c = nc;
                nc = c + h1; if (c < kr && nc >= kr) { chosen = btop - 1; kloc = kr - c; } c = nc;
                nc = c + h2; if (c < kr && nc >= kr) { chosen = btop - 2; kloc = kr - c; } c = nc;
                nc = c + h3; if (c < kr && nc >= kr) { chosen = btop - 3; kloc = kr - c; } c = nc;
                s_sel[0] = prefix | ((u32)chosen << shift);
                s_sel[1] = kloc;
            }
        }
        __syncthreads();
    }

    u32 tbits = s_sel[0];
    u32 kr = s_sel[1];
    float T = __uint_as_float(tbits);

    double sd = 0.0;
    for (int i = tid; i < P; i += 1024) {
        u32 v = __float_as_uint(s_mine[i]);
        if (v > tbits) sd += (double)s_mine[i];
    }
#pragma unroll
    for (int off = 32; off > 0; off >>= 1) sd += __shfl_xor(sd, off, 64);
    if (lane == 0) s_red[wave] = sd;
    __syncthreads();
    if (tid == 0) {
        double tt = 0.0;
#pragma unroll
        for (int w = 0; w < 16; w++) tt += s_red[w];
        pneg[b] = tt + (double)kr * (double)T;
    }
}

// Final: sum all partials, write both outputs.
__global__ void __launch_bounds__(1024) k_fin(const double* __restrict__ pl,
                                              const double* __restrict__ pc,
                                              const int* __restrict__ pn,
                                              const double* __restrict__ pneg,
                                              float* __restrict__ out) {
    const int tid = threadIdx.x;
    const int lane = tid & 63, wave = tid >> 6;
    __shared__ double s_l[16], s_c[16], s_g[16];
    __shared__ int s_t[16];

    double tl = 0.0, tc = 0.0, tg = 0.0;
    int tn = 0;
    for (int i = tid; i < NPART; i += 1024) { tl += pl[i]; tc += pc[i]; tn += pn[i]; }
    if (tid < B) tg = pneg[tid];
#pragma unroll
    for (int off = 32; off > 0; off >>= 1) {
        tl += __shfl_xor(tl, off, 64);
        tc += __shfl_xor(tc, off, 64);
        tg += __shfl_xor(tg, off, 64);
        tn += __shfl_xor(tn, off, 64);
    }
    if (lane == 0) { s_l[wave] = tl; s_c[wave] = tc; s_g[wave] = tg; s_t[wave] = tn; }
    __syncthreads();
    if (tid == 0) {
        double al = 0.0, ac = 0.0, ag = 0.0;
        int an = 0;
#pragma unroll
        for (int w = 0; w < 16; w++) { al += s_l[w]; ac += s_c[w]; ag += s_g[w]; an += s_t[w]; }
        double n = (double)an;
        out[0] = (float)(al / n);
        out[1] = (float)((ac + ag) / n);
    }
}

extern "C" void kernel_launch(void* const* d_in, const int* in_sizes, int n_in,
                              void* d_out, int out_size, void* d_ws, size_t ws_size,
                              hipStream_t stream) {
    const float* loc_preds = (const float*)d_in[0];
    const float* scores    = (const float*)d_in[1];
    const float* gt        = (const float*)d_in[2];
    const float* priors    = (const float*)d_in[3];

    char* ws = (char*)d_ws;
    u64* bk      = (u64*)ws;                  // [0, 131072)        B*O*NB1 u64
    double* pl   = (double*)(ws + 131072);    // [131072, 137216)   NPART=768 dbl
    double* pc   = (double*)(ws + 137216);    // [137216, 143360)
    int* pn      = (int*)(ws + 143360);       // [143360, 146432)
    double* pneg = (double*)(ws + 146432);    // [146432, 147456)
    u8* bidx     = (u8*)(ws + 147456);        // [147456, 1265152)  B*P u8
    float* mine  = (float*)(ws + 1265152);    // B*P*4 (16B-aligned)

    // no memset needed: every ws slot consumed is plainly overwritten each call

    k_pass1<<<dim3(NB1, B), dim3(256), 0, stream>>>(gt, priors, bk, bidx);
    k_pass2<<<dim3(NBX2, B), dim3(256), 0, stream>>>(
        gt, priors, bk, bidx, loc_preds, scores, mine, pl, pc, pn);
    k_hardneg<<<dim3(B), dim3(1024), 0, stream>>>(mine, pn, pneg);
    k_fin<<<dim3(1), dim3(1024), 0, stream>>>(pl, pc, pn, pneg, (float*)d_out);
}